// Round 2
// baseline (956.131 us; speedup 1.0000x reference)
//
#include <hip/hip_runtime.h>

typedef _Float16 half8 __attribute__((ext_vector_type(8)));
typedef float floatx16 __attribute__((ext_vector_type(16)));

#define B_   128
#define H_   4
#define SEQ_ 256
#define E_   64
#define D_   64
#define LH_  64
#define IN_  (LH_*E_)    // 4096
#define OUT_ (LH_*D_)    // 4096
#define QKV_MAT_ELEMS (B_*H_*OUT_)  // 2097152 halfs per matrix

__device__ __forceinline__ half8 cvt8(float4 lo, float4 hi) {
    half8 v;
    v[0] = (_Float16)lo.x; v[1] = (_Float16)lo.y;
    v[2] = (_Float16)lo.z; v[3] = (_Float16)lo.w;
    v[4] = (_Float16)hi.x; v[5] = (_Float16)hi.y;
    v[6] = (_Float16)hi.z; v[7] = (_Float16)hi.w;
    return v;
}

// ---------------------------------------------------------------------------
// Kernel 1: streaming QKV projection, NO LDS, NO barriers.
// Weights have zero reuse -> stream W rows straight into MFMA B-fragments.
// X rows streamed into A-fragments (L2-resident, 2MB/h slice).
// Block = 128 thr (2 waves); wave handles 64(m) x 64(n), accs 2x2 x 32x32.
// Grid 768 = 6 waves/CU; no barriers => loads stay in flight across k-iters.
// blockIdx swizzle: h = (i>>1)&3 so each h's X slice maps to one XCD pair.
// ---------------------------------------------------------------------------
__global__ __launch_bounds__(128) void qkv_gemm(
    const float* __restrict__ seq,
    const float* __restrict__ WQ, const float* __restrict__ bQ,
    const float* __restrict__ WK, const float* __restrict__ bK,
    const float* __restrict__ WV, const float* __restrict__ bV,
    _Float16* __restrict__ qkv)
{
    const int i   = blockIdx.x;
    const int h   = (i >> 1) & 3;
    const int sub = (i & 1) + ((i >> 3) << 1);   // [0,192)
    const int mat = sub >> 6;                     // 0..2
    const int nt  = sub & 63;
    const int o0  = nt * 64;

    const float* __restrict__ W    = (mat == 0) ? WQ : (mat == 1) ? WK : WV;
    const float* __restrict__ bias = (mat == 0) ? bQ : (mat == 1) ? bK : bV;

    const int wave = threadIdx.x >> 6;
    const int lane = threadIdx.x & 63;
    const int lrow = lane & 31;
    const int kg   = lane >> 5;
    const int m0   = wave * 64;

    // per-lane row base pointers (include kg*8 k-offset)
    const float* xr0 = seq + (size_t)(m0 + lrow) * (SEQ_*E_) + (size_t)h * IN_ + kg * 8;
    const float* xr1 = xr0 + (size_t)32 * (SEQ_*E_);
    const float* wr0 = W + (size_t)h * IN_ * OUT_ + (size_t)(o0 + lrow) * IN_ + kg * 8;
    const float* wr1 = wr0 + (size_t)32 * IN_;

    floatx16 acc00, acc01, acc10, acc11;
    #pragma unroll
    for (int r = 0; r < 16; ++r) { acc00[r]=0.f; acc01[r]=0.f; acc10[r]=0.f; acc11[r]=0.f; }

    for (int kt = 0; kt < 64; ++kt) {
        #pragma unroll
        for (int s = 0; s < 4; ++s) {
            const int k = kt * 64 + s * 16;
            float4 a0l = *(const float4*)(xr0 + k);
            float4 a0h = *(const float4*)(xr0 + k + 4);
            float4 a1l = *(const float4*)(xr1 + k);
            float4 a1h = *(const float4*)(xr1 + k + 4);
            float4 b0l = *(const float4*)(wr0 + k);
            float4 b0h = *(const float4*)(wr0 + k + 4);
            float4 b1l = *(const float4*)(wr1 + k);
            float4 b1h = *(const float4*)(wr1 + k + 4);
            half8 a0 = cvt8(a0l, a0h);
            half8 a1 = cvt8(a1l, a1h);
            half8 b0 = cvt8(b0l, b0h);
            half8 b1 = cvt8(b1l, b1h);
            acc00 = __builtin_amdgcn_mfma_f32_32x32x16_f16(a0, b0, acc00, 0, 0, 0);
            acc01 = __builtin_amdgcn_mfma_f32_32x32x16_f16(a0, b1, acc01, 0, 0, 0);
            acc10 = __builtin_amdgcn_mfma_f32_32x32x16_f16(a1, b0, acc10, 0, 0, 0);
            acc11 = __builtin_amdgcn_mfma_f32_32x32x16_f16(a1, b1, acc11, 0, 0, 0);
        }
    }

    // epilogue: C/D layout col = lane&31, row = (r&3) + 8*(r>>2) + 4*(lane>>5)
    const float bv0 = bias[(size_t)h * OUT_ + o0 + lrow];
    const float bv1 = bias[(size_t)h * OUT_ + o0 + 32 + lrow];
    _Float16* dst = qkv + (size_t)mat * QKV_MAT_ELEMS;
    #pragma unroll
    for (int r = 0; r < 16; ++r) {
        const int row = (r & 3) + 8 * (r >> 2) + 4 * kg;
        const int b0r = m0 + row;
        const int b1r = m0 + 32 + row;
        size_t i0 = ((size_t)(b0r * H_ + h)) * OUT_ + o0;
        size_t i1 = ((size_t)(b1r * H_ + h)) * OUT_ + o0;
        dst[i0 + lrow]      = (_Float16)(acc00[r] + bv0);
        dst[i0 + 32 + lrow] = (_Float16)(acc01[r] + bv1);
        dst[i1 + lrow]      = (_Float16)(acc10[r] + bv0);
        dst[i1 + 32 + lrow] = (_Float16)(acc11[r] + bv1);
    }
}

// ---------------------------------------------------------------------------
// Kernel 2: per-(b,h) local attention, MFMA everywhere.
// S = Q.K^T via f16 MFMA (frags straight from global, no cvt).
// Column softmax (over q, faithful to reference axis=2) done on the C-layout:
// each lane holds 16 rows of ONE column; shfl_xor(32) + 2x64 LDS exchange.
// 1/colsum * 0.125 folded into V during its LDS-transpose staging.
// Z = P.V via f16 MFMA from swizzled LDS.
// ---------------------------------------------------------------------------
__global__ __launch_bounds__(256) void local_attn(
    const _Float16* __restrict__ qkv, float* __restrict__ out)
{
    __shared__ half8 Pf[64 * 8];      // P[q][k] f16, swizzled units (8 KB)
    __shared__ half8 Vt[64 * 8];      // V^T[d][k] f16, swizzled units (8 KB)
    __shared__ float redM[2][64];
    __shared__ float redS[2][64];
    __shared__ float invL[64];

    const int t = threadIdx.x;
    const int h = blockIdx.x;
    const int b = blockIdx.y;
    const size_t base = ((size_t)(b * H_ + h)) * OUT_;

    const _Float16* Q = qkv + base;
    const _Float16* K = qkv + (size_t)QKV_MAT_ELEMS + base;
    const _Float16* V = qkv + (size_t)2 * QKV_MAT_ELEMS + base;

    // prefetch V early (consumed in phase 4)
    half8 v0 = *(const half8*)(V + (size_t)t * 8);          // unit t:   k=t>>3,  d8=t&7
    half8 v1 = *(const half8*)(V + (size_t)(t + 256) * 8);  // unit t+256

    const int wave = t >> 6, lane = t & 63;
    const int lrow = lane & 31, kg = lane >> 5;
    const int qt = wave >> 1, kt = wave & 1;   // S-tile (q-tile, k-tile)

    // ---- S = Q.K^T (one 32x32 tile per wave) ----
    floatx16 s;
    #pragma unroll
    for (int r = 0; r < 16; ++r) s[r] = 0.f;
    #pragma unroll
    for (int st = 0; st < 4; ++st) {
        half8 a  = *(const half8*)(Q + (qt * 32 + lrow) * 64 + st * 16 + kg * 8);
        half8 bb = *(const half8*)(K + (kt * 32 + lrow) * 64 + st * 16 + kg * 8);
        s = __builtin_amdgcn_mfma_f32_32x32x16_f16(a, bb, s, 0, 0, 0);
    }

    // ---- mask (k > q -> -1e20) + in-lane column max ----
    const int col = kt * 32 + lrow;     // global k index this lane owns
    float m = -3.4e38f;
    #pragma unroll
    for (int r = 0; r < 16; ++r) {
        const int q = qt * 32 + (r & 3) + 8 * (r >> 2) + 4 * kg;
        if (col > q) s[r] = -1e20f;
        m = fmaxf(m, s[r]);
    }
    m = fmaxf(m, __shfl_xor(m, 32));    // other 16 rows of this column (same tile)
    redM[qt][col] = m;
    __syncthreads();
    m = fmaxf(redM[0][col], redM[1][col]);

    // ---- exp + column sum ----
    float sum = 0.f;
    #pragma unroll
    for (int r = 0; r < 16; ++r) {
        float e = __expf(s[r] - m);
        s[r] = e;
        sum += e;
    }
    sum += __shfl_xor(sum, 32);
    redS[qt][col] = sum;
    __syncthreads();
    const float inv = 1.f / (redS[0][col] + redS[1][col]);
    if (qt == 0 && kg == 0) invL[col] = inv * 0.125f;   // fold softmax norm + 1/sqrt(D)

    // ---- write P (unnormalized exp, <=1) as f16, swizzled ----
    {
        _Float16* p = (_Float16*)Pf;
        const int k8 = col >> 3;
        #pragma unroll
        for (int r = 0; r < 16; ++r) {
            const int q = qt * 32 + (r & 3) + 8 * (r >> 2) + 4 * kg;
            p[(q * 8 + (k8 ^ (q & 7))) * 8 + (col & 7)] = (_Float16)s[r];
        }
    }
    __syncthreads();   // Pf + invL visible

    // ---- stage V^T with inv[k]*0.125 folded in ----
    {
        _Float16* vt = (_Float16*)Vt;
        const int k0 = t >> 3, d80 = t & 7;
        const float iv0 = invL[k0];
        #pragma unroll
        for (int j = 0; j < 8; ++j) {
            const int d = d80 * 8 + j;
            vt[(d * 8 + ((k0 >> 3) ^ (d & 7))) * 8 + (k0 & 7)] = (_Float16)((float)v0[j] * iv0);
        }
        const int k1 = (t + 256) >> 3;
        const float iv1 = invL[k1];
        #pragma unroll
        for (int j = 0; j < 8; ++j) {
            const int d = d80 * 8 + j;
            vt[(d * 8 + ((k1 >> 3) ^ (d & 7))) * 8 + (k1 & 7)] = (_Float16)((float)v1[j] * iv1);
        }
    }
    __syncthreads();

    // ---- Z = P.V (one 32x32 tile per wave: q-tile qt, d-tile kt) ----
    const int dt = kt;
    floatx16 z;
    #pragma unroll
    for (int r = 0; r < 16; ++r) z[r] = 0.f;
    #pragma unroll
    for (int st = 0; st < 4; ++st) {
        const int k8 = st * 2 + kg;
        const int q  = qt * 32 + lrow;
        const int d  = dt * 32 + lrow;
        half8 a  = Pf[q * 8 + (k8 ^ (q & 7))];
        half8 bb = Vt[d * 8 + (k8 ^ (d & 7))];
        z = __builtin_amdgcn_mfma_f32_32x32x16_f16(a, bb, z, 0, 0, 0);
    }
    #pragma unroll
    for (int r = 0; r < 16; ++r) {
        const int q = qt * 32 + (r & 3) + 8 * (r >> 2) + 4 * kg;
        const int d = dt * 32 + lrow;
        out[((size_t)b * SEQ_ + h * LH_ + q) * D_ + d] = z[r];
    }
}

extern "C" void kernel_launch(void* const* d_in, const int* in_sizes, int n_in,
                              void* d_out, int out_size, void* d_ws, size_t ws_size,
                              hipStream_t stream)
{
    const float* seq = (const float*)d_in[0];
    const float* WQ  = (const float*)d_in[1];
    const float* bQ  = (const float*)d_in[2];
    const float* WK  = (const float*)d_in[3];
    const float* bK  = (const float*)d_in[4];
    const float* WV  = (const float*)d_in[5];
    const float* bV  = (const float*)d_in[6];
    _Float16* qkv = (_Float16*)d_ws;      // 3 * 2097152 halfs = 12.6 MB
    float* out = (float*)d_out;

    qkv_gemm<<<768, 128, 0, stream>>>(seq, WQ, bQ, WK, bK, WV, bV, qkv);
    dim3 g2(H_, B_);
    local_attn<<<g2, 256, 0, stream>>>(qkv, out);
}

// Round 3
// 798.228 us; speedup vs baseline: 1.1978x; 1.1978x over previous
//
#include <hip/hip_runtime.h>

typedef _Float16 half8 __attribute__((ext_vector_type(8)));
typedef float floatx16 __attribute__((ext_vector_type(16)));

#define B_   128
#define H_   4
#define SEQ_ 256
#define E_   64
#define D_   64
#define LH_  64
#define IN_  (LH_*E_)    // 4096
#define OUT_ (LH_*D_)    // 4096
#define QKV_MAT_ELEMS (B_*H_*OUT_)  // 2097152 halfs per matrix

// W-stage LDS layout: 16 DMA units of 1KB (4 rows x 256B) + 16B pad/unit.
#define UNIT_B  1040
#define STAGE_B (16 * UNIT_B)   // 16640 B per stage; 3 stages = 49920 B

__device__ __forceinline__ half8 cvt8(float4 lo, float4 hi) {
    half8 v;
    v[0] = (_Float16)lo.x; v[1] = (_Float16)lo.y;
    v[2] = (_Float16)lo.z; v[3] = (_Float16)lo.w;
    v[4] = (_Float16)hi.x; v[5] = (_Float16)hi.y;
    v[6] = (_Float16)hi.z; v[7] = (_Float16)hi.w;
    return v;
}

// ---------------------------------------------------------------------------
// Kernel 1: QKV projection. W streamed HBM->LDS via async global_load_lds
// (width 16, no dest VGPRs -> deep HBM queue), 3-stage circular buffer,
// fine-grained s_waitcnt vmcnt(4) + raw s_barrier (never vmcnt(0)).
// X (8 MB) read to registers from L2 (h -> XCD-pair swizzle keeps the 2MB
// slice resident). Block 256 thr = 4 waves; C-tile 128(m) x 64(n);
// wave w: rows [w*32, w*32+32), both 32-col halves -> 2 accs.
// ---------------------------------------------------------------------------
__global__ __launch_bounds__(256, 3) void qkv_gemm(
    const float* __restrict__ seq,
    const float* __restrict__ WQ, const float* __restrict__ bQ,
    const float* __restrict__ WK, const float* __restrict__ bK,
    const float* __restrict__ WV, const float* __restrict__ bV,
    _Float16* __restrict__ qkv)
{
    __shared__ alignas(16) char smem[3 * STAGE_B];

    const int i   = blockIdx.x;
    const int h   = (i >> 1) & 3;                // XCD-pair locality for X
    const int sub = (i & 1) + ((i >> 3) << 1);   // [0,192)
    const int mat = sub >> 6;
    const int nt  = sub & 63;
    const int o0  = nt * 64;

    const float* __restrict__ W    = (mat == 0) ? WQ : (mat == 1) ? WK : WV;
    const float* __restrict__ bias = (mat == 0) ? bQ : (mat == 1) ? bK : bV;
    const float* __restrict__ Wblk = W + (size_t)h * IN_ * OUT_ + (size_t)o0 * IN_;

    const int t    = threadIdx.x;
    const int wave = t >> 6;
    const int lane = t & 63;
    const int lrow = lane & 31;
    const int kg   = lane >> 5;

    // per-thread DMA source pieces: unit u = j*4+wave, row = u*4 + (lane>>4),
    // 16B chunk (lane&15) within the row's 256B k-slice.
    const int dmarow_sub = lane >> 4;
    const int dmacol     = (lane & 15) * 4;

    // A source: X row (batch) wave*32+lrow, this lane's kg*8 float offset.
    const float* xr = seq + (size_t)(wave * 32 + lrow) * (SEQ_ * E_)
                          + (size_t)h * IN_ + kg * 8;

    floatx16 acc0, acc1;
    #pragma unroll
    for (int r = 0; r < 16; ++r) { acc0[r] = 0.f; acc1[r] = 0.f; }

    auto issue = [&](int ktile, int buf) {
        char* sb = smem + buf * STAGE_B;
        #pragma unroll
        for (int j = 0; j < 4; ++j) {
            const int u   = j * 4 + wave;
            const int row = u * 4 + dmarow_sub;
            const float* g = Wblk + (size_t)row * IN_ + ktile * 64 + dmacol;
            __builtin_amdgcn_global_load_lds(
                (const __attribute__((address_space(1))) void*)g,
                (__attribute__((address_space(3))) void*)(sb + u * UNIT_B),
                16, 0, 0);
        }
    };

    issue(0, 0);
    issue(1, 1);

    // fragment LDS base for this lane's two B rows (r, r+32)
    const int fragoff = (lrow >> 2) * UNIT_B + (lrow & 3) * 256 + kg * 32;

    for (int kt = 0; kt < 64; ++kt) {
        // wait own stage-kt DMA done (leave stage kt+1's 4 instrs in flight)
        __atomic_signal_fence(__ATOMIC_ACQ_REL);
        __builtin_amdgcn_s_waitcnt(0xF74);   // vmcnt(4), lgkm/exp ignored
        __builtin_amdgcn_s_barrier();        // raw barrier: no vmcnt(0) drain
        __atomic_signal_fence(__ATOMIC_ACQ_REL);

        // A loads first (so compiler's A-waits leave the W prefetch in flight)
        const float* xk = xr + kt * 64;
        float4 a[8];
        #pragma unroll
        for (int s2 = 0; s2 < 4; ++s2) {
            a[2 * s2]     = *(const float4*)(xk + s2 * 16);
            a[2 * s2 + 1] = *(const float4*)(xk + s2 * 16 + 4);
        }

        // prefetch stage kt+2 into buffer (kt+2)%3 (safe: all waves passed
        // the barrier, so reads of that buffer from iter kt-1 are complete).
        // kt=62,63 issue a harmless duplicate of k-tile 63 (never read) to
        // keep the vmcnt arithmetic uniform.
        issue((kt + 2 <= 63) ? kt + 2 : 63, (kt + 2) % 3);
        __atomic_signal_fence(__ATOMIC_ACQ_REL);

        const char* stb = smem + (kt % 3) * STAGE_B + fragoff;
        #pragma unroll
        for (int s2 = 0; s2 < 4; ++s2) {
            half8 af = cvt8(a[2 * s2], a[2 * s2 + 1]);
            const char* p0 = stb + s2 * 64;
            const char* p1 = p0 + 8 * UNIT_B;   // row +32
            float4 b0l = *(const float4*)p0;
            float4 b0h = *(const float4*)(p0 + 16);
            float4 b1l = *(const float4*)p1;
            float4 b1h = *(const float4*)(p1 + 16);
            half8 bf0 = cvt8(b0l, b0h);
            half8 bf1 = cvt8(b1l, b1h);
            acc0 = __builtin_amdgcn_mfma_f32_32x32x16_f16(af, bf0, acc0, 0, 0, 0);
            acc1 = __builtin_amdgcn_mfma_f32_32x32x16_f16(af, bf1, acc1, 0, 0, 0);
        }
    }

    // epilogue: C/D layout col = lane&31, row = (r&3) + 8*(r>>2) + 4*(lane>>5)
    const float bv0 = bias[(size_t)h * OUT_ + o0 + lrow];
    const float bv1 = bias[(size_t)h * OUT_ + o0 + 32 + lrow];
    _Float16* dst = qkv + (size_t)mat * QKV_MAT_ELEMS;
    #pragma unroll
    for (int r = 0; r < 16; ++r) {
        const int row = (r & 3) + 8 * (r >> 2) + 4 * kg;
        const int b   = wave * 32 + row;
        size_t idx = ((size_t)(b * H_ + h)) * OUT_ + o0;
        dst[idx + lrow]      = (_Float16)(acc0[r] + bv0);
        dst[idx + 32 + lrow] = (_Float16)(acc1[r] + bv1);
    }
}

// ---------------------------------------------------------------------------
// Kernel 2: per-(b,h) local attention, MFMA everywhere (unchanged from R2,
// passed with absmax 0.0078).
// ---------------------------------------------------------------------------
__global__ __launch_bounds__(256) void local_attn(
    const _Float16* __restrict__ qkv, float* __restrict__ out)
{
    __shared__ half8 Pf[64 * 8];
    __shared__ half8 Vt[64 * 8];
    __shared__ float redM[2][64];
    __shared__ float redS[2][64];
    __shared__ float invL[64];

    const int t = threadIdx.x;
    const int h = blockIdx.x;
    const int b = blockIdx.y;
    const size_t base = ((size_t)(b * H_ + h)) * OUT_;

    const _Float16* Q = qkv + base;
    const _Float16* K = qkv + (size_t)QKV_MAT_ELEMS + base;
    const _Float16* V = qkv + (size_t)2 * QKV_MAT_ELEMS + base;

    half8 v0 = *(const half8*)(V + (size_t)t * 8);
    half8 v1 = *(const half8*)(V + (size_t)(t + 256) * 8);

    const int wave = t >> 6, lane = t & 63;
    const int lrow = lane & 31, kg = lane >> 5;
    const int qt = wave >> 1, kt = wave & 1;

    floatx16 s;
    #pragma unroll
    for (int r = 0; r < 16; ++r) s[r] = 0.f;
    #pragma unroll
    for (int st = 0; st < 4; ++st) {
        half8 a  = *(const half8*)(Q + (qt * 32 + lrow) * 64 + st * 16 + kg * 8);
        half8 bb = *(const half8*)(K + (kt * 32 + lrow) * 64 + st * 16 + kg * 8);
        s = __builtin_amdgcn_mfma_f32_32x32x16_f16(a, bb, s, 0, 0, 0);
    }

    const int col = kt * 32 + lrow;
    float m = -3.4e38f;
    #pragma unroll
    for (int r = 0; r < 16; ++r) {
        const int q = qt * 32 + (r & 3) + 8 * (r >> 2) + 4 * kg;
        if (col > q) s[r] = -1e20f;
        m = fmaxf(m, s[r]);
    }
    m = fmaxf(m, __shfl_xor(m, 32));
    redM[qt][col] = m;
    __syncthreads();
    m = fmaxf(redM[0][col], redM[1][col]);

    float sum = 0.f;
    #pragma unroll
    for (int r = 0; r < 16; ++r) {
        float e = __expf(s[r] - m);
        s[r] = e;
        sum += e;
    }
    sum += __shfl_xor(sum, 32);
    redS[qt][col] = sum;
    __syncthreads();
    const float inv = 1.f / (redS[0][col] + redS[1][col]);
    if (qt == 0 && kg == 0) invL[col] = inv * 0.125f;

    {
        _Float16* p = (_Float16*)Pf;
        const int k8 = col >> 3;
        #pragma unroll
        for (int r = 0; r < 16; ++r) {
            const int q = qt * 32 + (r & 3) + 8 * (r >> 2) + 4 * kg;
            p[(q * 8 + (k8 ^ (q & 7))) * 8 + (col & 7)] = (_Float16)s[r];
        }
    }
    __syncthreads();

    {
        _Float16* vt = (_Float16*)Vt;
        const int k0 = t >> 3, d80 = t & 7;
        const float iv0 = invL[k0];
        #pragma unroll
        for (int j = 0; j < 8; ++j) {
            const int d = d80 * 8 + j;
            vt[(d * 8 + ((k0 >> 3) ^ (d & 7))) * 8 + (k0 & 7)] = (_Float16)((float)v0[j] * iv0);
        }
        const int k1 = (t + 256) >> 3;
        const float iv1 = invL[k1];
        #pragma unroll
        for (int j = 0; j < 8; ++j) {
            const int d = d80 * 8 + j;
            vt[(d * 8 + ((k1 >> 3) ^ (d & 7))) * 8 + (k1 & 7)] = (_Float16)((float)v1[j] * iv1);
        }
    }
    __syncthreads();

    const int dt = kt;
    floatx16 z;
    #pragma unroll
    for (int r = 0; r < 16; ++r) z[r] = 0.f;
    #pragma unroll
    for (int st = 0; st < 4; ++st) {
        const int k8 = st * 2 + kg;
        const int q  = qt * 32 + lrow;
        const int d  = dt * 32 + lrow;
        half8 a  = Pf[q * 8 + (k8 ^ (q & 7))];
        half8 bb = Vt[d * 8 + (k8 ^ (d & 7))];
        z = __builtin_amdgcn_mfma_f32_32x32x16_f16(a, bb, z, 0, 0, 0);
    }
    #pragma unroll
    for (int r = 0; r < 16; ++r) {
        const int q = qt * 32 + (r & 3) + 8 * (r >> 2) + 4 * kg;
        const int d = dt * 32 + lrow;
        out[((size_t)b * SEQ_ + h * LH_ + q) * D_ + d] = z[r];
    }
}

extern "C" void kernel_launch(void* const* d_in, const int* in_sizes, int n_in,
                              void* d_out, int out_size, void* d_ws, size_t ws_size,
                              hipStream_t stream)
{
    const float* seq = (const float*)d_in[0];
    const float* WQ  = (const float*)d_in[1];
    const float* bQ  = (const float*)d_in[2];
    const float* WK  = (const float*)d_in[3];
    const float* bK  = (const float*)d_in[4];
    const float* WV  = (const float*)d_in[5];
    const float* bV  = (const float*)d_in[6];
    _Float16* qkv = (_Float16*)d_ws;      // 12.6 MB
    float* out = (float*)d_out;

    qkv_gemm<<<768, 256, 0, stream>>>(seq, WQ, bQ, WK, bK, WV, bV, qkv);
    dim3 g2(H_, B_);
    local_attn<<<g2, 256, 0, stream>>>(qkv, out);
}